// Round 6
// baseline (246.244 us; speedup 1.0000x reference)
//
#include <hip/hip_runtime.h>
#include <cmath>

#define DIM 128
#define NHALF 4096
#define NROWS 8192
#define NSTRIPS 128  // 64-row strips
#define NTILES 8256  // 128*129/2 upper-triangle 64x64 tiles
#define NBLOCKS 2064 // 4 independent waves/block, 1 tile/wave
// FRAG_SCALE^2 = log2(e)/tau = 1.4426950408889634/0.5
#define FRAG_SCALE 1.69864368f

typedef __attribute__((ext_vector_type(4))) float f32x4;

// One wave per pair r: L2-normalize z_i[r], z_j[r], scale by sqrt(log2e/tau),
// quantize to fp8 e4m3 rows r and r+4096 (2 bytes/lane). pos in exact fp32.
// Zero rowsum + tile counter.
__global__ __launch_bounds__(256) void prep_kernel(
    const float* __restrict__ z_i, const float* __restrict__ z_j,
    unsigned char* __restrict__ A, float* __restrict__ rowsum,
    float* __restrict__ pos, unsigned int* __restrict__ counter) {
  int wave = threadIdx.x >> 6;
  int lane = threadIdx.x & 63;
  int r = blockIdx.x * 4 + wave;
  float2 a = *(const float2*)(z_i + (size_t)r * DIM + 2 * lane);
  float2 b = *(const float2*)(z_j + (size_t)r * DIM + 2 * lane);
  float sa = a.x * a.x + a.y * a.y;
  float sb = b.x * b.x + b.y * b.y;
  float dp = a.x * b.x + a.y * b.y;
#pragma unroll
  for (int off = 1; off < 64; off <<= 1) {
    sa += __shfl_xor(sa, off);
    sb += __shfl_xor(sb, off);
    dp += __shfl_xor(dp, off);
  }
  float na = fmaxf(sqrtf(sa), 1e-8f);
  float nb = fmaxf(sqrtf(sb), 1e-8f);
  float si = FRAG_SCALE / na;
  float sj = FRAG_SCALE / nb;
  int pa = __builtin_amdgcn_cvt_pk_fp8_f32(a.x * si, a.y * si, 0, false);
  int pb = __builtin_amdgcn_cvt_pk_fp8_f32(b.x * sj, b.y * sj, 0, false);
  ((unsigned short*)A)[(size_t)r * (DIM / 2) + lane] = (unsigned short)pa;
  ((unsigned short*)A)[(size_t)(r + NHALF) * (DIM / 2) + lane] =
      (unsigned short)pb;
  if (lane == 0) {
    float p = dp / (na * nb) * 2.0f;  // /tau, tau=0.5
    pos[r] = p;
    pos[r + NHALF] = p;
    rowsum[r] = 0.0f;
    rowsum[r + NHALF] = 0.0f;
    if (r == 0) *counter = 0u;
  }
}

// One 64x64 upper-triangle tile per WAVE (8256 tiles, 2064 blocks, no
// __syncthreads in main path). fp8 fragments straight from L2: 16 loads of
// 16B/lane per wave (each ulonglong2 = two K-chunk fragments; K-permutation
// is shared by A and B so any within-lane k order is correct). 64 MFMAs,
// exp2 epilogue with row+col (symmetry) credit, fused last-block finalize.
__global__ __launch_bounds__(256, 3) void simexp_kernel(
    const unsigned char* __restrict__ Amat, float* __restrict__ rowsum,
    const float* __restrict__ pos, unsigned int* __restrict__ counter,
    float* __restrict__ out) {
  const int tid = threadIdx.x;
  const int lane = tid & 63;
  const int w = tid >> 6;
  const int q = lane >> 4;
  const int n = lane & 15;

  // tile index -> (bi, bj), bi <= bj over 128 strips
  int t = blockIdx.x * 4 + w;
  int bi = (int)((257.0f - sqrtf(66049.0f - 8.0f * (float)t)) * 0.5f);
  bi = (bi < 0) ? 0 : ((bi > 127) ? 127 : bi);
  int start = 128 * bi - (bi * (bi - 1)) / 2;
  while (t < start) {
    --bi;
    start = 128 * bi - (bi * (bi - 1)) / 2;
  }
  while (t >= start + (NSTRIPS - bi)) {
    start += NSTRIPS - bi;
    ++bi;
  }
  const int bj = bi + (t - start);
  const int rb = bi * 64;
  const int cb = bj * 64;
  const bool diag = (bi == bj);

  const unsigned char* Ag = Amat + (size_t)rb * DIM;
  const unsigned char* Bg = Amat + (size_t)cb * DIM;

  // all 16 fragment loads issued up front (16B each, 16 rows x 64B pattern)
  ulonglong2 Af[4][2], Bf[4][2];
#pragma unroll
  for (int h = 0; h < 2; h++) {
#pragma unroll
    for (int mi = 0; mi < 4; mi++)
      Af[mi][h] =
          *(const ulonglong2*)(Ag + (size_t)(mi * 16 + n) * DIM + h * 64 + q * 16);
#pragma unroll
    for (int ni = 0; ni < 4; ni++)
      Bf[ni][h] =
          *(const ulonglong2*)(Bg + (size_t)(ni * 16 + n) * DIM + h * 64 + q * 16);
  }

  f32x4 acc[16];
#pragma unroll
  for (int i = 0; i < 16; i++)
#pragma unroll
    for (int j = 0; j < 4; j++) acc[i][j] = 0.0f;

#pragma unroll
  for (int h = 0; h < 2; h++)
#pragma unroll
    for (int mi = 0; mi < 4; mi++)
#pragma unroll
      for (int ni = 0; ni < 4; ni++) {
        acc[mi * 4 + ni] = __builtin_amdgcn_mfma_f32_16x16x32_fp8_fp8(
            (long long)Af[mi][h].x, (long long)Bf[ni][h].x, acc[mi * 4 + ni],
            0, 0, 0);
        acc[mi * 4 + ni] = __builtin_amdgcn_mfma_f32_16x16x32_fp8_fp8(
            (long long)Af[mi][h].y, (long long)Bf[ni][h].y, acc[mi * 4 + ni],
            0, 0, 0);
      }

  // epilogue: exp2, diagonal mask (wave-uniform branch), row + col credit
  float eaccR[16];
  float eaccC[4] = {0.0f, 0.0f, 0.0f, 0.0f};
#pragma unroll
  for (int i = 0; i < 16; i++) eaccR[i] = 0.0f;

  if (diag) {
#pragma unroll
    for (int mi = 0; mi < 4; mi++)
#pragma unroll
      for (int ni = 0; ni < 4; ni++)
#pragma unroll
        for (int rg = 0; rg < 4; rg++) {
          int lrow = mi * 16 + q * 4 + rg;
          int lcol = ni * 16 + n;
          float e = __builtin_amdgcn_exp2f(acc[mi * 4 + ni][rg]);
          eaccR[mi * 4 + rg] += (lrow == lcol) ? 0.0f : e;
        }
  } else {
#pragma unroll
    for (int mi = 0; mi < 4; mi++)
#pragma unroll
      for (int ni = 0; ni < 4; ni++)
#pragma unroll
        for (int rg = 0; rg < 4; rg++) {
          float e = __builtin_amdgcn_exp2f(acc[mi * 4 + ni][rg]);
          eaccR[mi * 4 + rg] += e;
          eaccC[ni] += e;
        }
  }

  // row credit: reduce over n, one lane-0 atomic per row (16 rows/wave... 64)
#pragma unroll
  for (int mi = 0; mi < 4; mi++)
#pragma unroll
    for (int rg = 0; rg < 4; rg++) {
      float v = eaccR[mi * 4 + rg];
      v += __shfl_xor(v, 1);
      v += __shfl_xor(v, 2);
      v += __shfl_xor(v, 4);
      v += __shfl_xor(v, 8);
      if (n == 0) atomicAdd(&rowsum[rb + mi * 16 + q * 4 + rg], v);
    }
  // column credit for off-diagonal tiles
  if (!diag) {
#pragma unroll
    for (int ni = 0; ni < 4; ni++) {
      float v = eaccC[ni];
      v += __shfl_xor(v, 16);
      v += __shfl_xor(v, 32);
      if (lane < 16) atomicAdd(&rowsum[cb + ni * 16 + n], v);
    }
  }

  // last-block finalize: loss = mean(log(rowsum) - pos)
  __threadfence();
  __shared__ unsigned int lastFlag;
  if (tid == 0) {
    unsigned int old = __hip_atomic_fetch_add(counter, 1u, __ATOMIC_ACQ_REL,
                                              __HIP_MEMORY_SCOPE_AGENT);
    lastFlag = (old == NBLOCKS - 1) ? 1u : 0u;
  }
  __syncthreads();
  if (lastFlag) {
    float local = 0.0f;
    for (int r = tid; r < NROWS; r += 256) {
      float rs = __hip_atomic_load(&rowsum[r], __ATOMIC_RELAXED,
                                   __HIP_MEMORY_SCOPE_AGENT);
      local += __logf(rs) - pos[r];
    }
#pragma unroll
    for (int off = 1; off < 64; off <<= 1) local += __shfl_xor(local, off);
    __shared__ float wsum[4];
    if (lane == 0) wsum[w] = local;
    __syncthreads();
    if (tid == 0)
      out[0] = (wsum[0] + wsum[1] + wsum[2] + wsum[3]) * (1.0f / (float)NROWS);
  }
}

extern "C" void kernel_launch(void* const* d_in, const int* in_sizes, int n_in,
                              void* d_out, int out_size, void* d_ws,
                              size_t ws_size, hipStream_t stream) {
  const float* z_i = (const float*)d_in[0];
  const float* z_j = (const float*)d_in[1];
  float* out = (float*)d_out;

  unsigned char* A = (unsigned char*)d_ws;               // 8192*128 fp8 = 1 MB
  float* rowsum = (float*)((char*)d_ws + 1048576);       // 32 KB
  float* pos = (float*)((char*)d_ws + 1048576 + 32768);  // 32 KB
  unsigned int* counter = (unsigned int*)((char*)d_ws + 1048576 + 65536);

  prep_kernel<<<NHALF / 4, 256, 0, stream>>>(z_i, z_j, A, rowsum, pos, counter);
  simexp_kernel<<<NBLOCKS, 256, 0, stream>>>(A, rowsum, pos, counter, out);
}

// Round 7
// 243.800 us; speedup vs baseline: 1.0100x; 1.0100x over previous
//
#include <hip/hip_runtime.h>
#include <cmath>

#define DIM 128
#define NHALF 4096
#define NROWS 8192
#define NTILES 2080  // 64*65/2 upper-triangle 128x128 tiles
// FRAG_SCALE^2 = log2(e)/tau = 1.4426950408889634/0.5
#define FRAG_SCALE 1.69864368f

typedef __attribute__((ext_vector_type(4))) float f32x4;

// One wave per pair r: L2-normalize z_i[r], z_j[r], scale by sqrt(log2e/tau),
// quantize to fp8 e4m3 rows r and r+4096. pos computed in exact fp32.
// Zeroes rowsum + tile counter.
__global__ __launch_bounds__(256) void prep_kernel(
    const float* __restrict__ z_i, const float* __restrict__ z_j,
    unsigned char* __restrict__ A, float* __restrict__ rowsum,
    float* __restrict__ pos, unsigned int* __restrict__ counter) {
  int wave = threadIdx.x >> 6;
  int lane = threadIdx.x & 63;
  int r = blockIdx.x * 4 + wave;
  float2 a = *(const float2*)(z_i + (size_t)r * DIM + 2 * lane);
  float2 b = *(const float2*)(z_j + (size_t)r * DIM + 2 * lane);
  float sa = a.x * a.x + a.y * a.y;
  float sb = b.x * b.x + b.y * b.y;
  float dp = a.x * b.x + a.y * b.y;
#pragma unroll
  for (int off = 1; off < 64; off <<= 1) {
    sa += __shfl_xor(sa, off);
    sb += __shfl_xor(sb, off);
    dp += __shfl_xor(dp, off);
  }
  float na = fmaxf(sqrtf(sa), 1e-8f);
  float nb = fmaxf(sqrtf(sb), 1e-8f);
  float si = FRAG_SCALE / na;
  float sj = FRAG_SCALE / nb;
  int pa = __builtin_amdgcn_cvt_pk_fp8_f32(a.x * si, a.y * si, 0, false);
  int pb = __builtin_amdgcn_cvt_pk_fp8_f32(b.x * sj, b.y * sj, 0, false);
  ((unsigned short*)A)[(size_t)r * (DIM / 2) + lane] = (unsigned short)pa;
  ((unsigned short*)A)[(size_t)(r + NHALF) * (DIM / 2) + lane] =
      (unsigned short)pb;
  if (lane == 0) {
    float p = dp / (na * nb) * 2.0f;  // /tau, tau=0.5
    pos[r] = p;
    pos[r + NHALF] = p;
    rowsum[r] = 0.0f;
    rowsum[r + NHALF] = 0.0f;
    if (r == 0) *counter = 0u;
  }
}

// R2 skeleton, fp8: upper-triangle 128x128 tiles, one per block, 4 quadrant
// waves (A-rows / B-rows each shared by 2 waves -> L1 reuse). LDS-free:
// fragments straight from L2. Interleaved h-loop: 8 x 16B loads then 32
// MFMAs (keeps waves out of lockstep convoys). 16B/lane covers two K=32
// chunks; K-permutation is identical for A and B so the dot is exact.
// exp2 epilogue with row+col (symmetry) credit; fused last-block finalize.
__global__ __launch_bounds__(256) void simexp_kernel(
    const unsigned char* __restrict__ Amat, float* __restrict__ rowsum,
    const float* __restrict__ pos, unsigned int* __restrict__ counter,
    float* __restrict__ out) {
  const int tid = threadIdx.x;
  const int lane = tid & 63;
  const int w = tid >> 6;
  const int q = lane >> 4;
  const int n = lane & 15;

  // decode upper-triangle tile index t -> (bi, bj), bi <= bj, 64 strips
  int t = blockIdx.x;
  int bi = (int)((129.0f - sqrtf(16641.0f - 8.0f * (float)t)) * 0.5f);
  int start = 64 * bi - (bi * (bi - 1)) / 2;
  if (t < start) {
    bi--;
    start = 64 * bi - (bi * (bi - 1)) / 2;
  } else if (t >= start + (64 - bi)) {
    start += 64 - bi;
    bi++;
  }
  int bj = bi + (t - start);

  const int rbBase = bi * 128;
  const int cbBase = bj * 128;
  const bool diag = (bi == bj);
  const int wrow = (w & 1) * 64;
  const int wcol = (w >> 1) * 64;

  const unsigned char* Ag = Amat + (size_t)(rbBase + wrow) * DIM;
  const unsigned char* Bg = Amat + (size_t)(cbBase + wcol) * DIM;

  f32x4 acc[16];
#pragma unroll
  for (int i = 0; i < 16; i++)
#pragma unroll
    for (int j = 0; j < 4; j++) acc[i][j] = 0.0f;

#pragma unroll
  for (int h = 0; h < 2; h++) {
    ulonglong2 af[4], bfr[4];
#pragma unroll
    for (int mi = 0; mi < 4; mi++)
      af[mi] = *(const ulonglong2*)(Ag + (size_t)(mi * 16 + n) * DIM + h * 64 +
                                    q * 16);
#pragma unroll
    for (int ni = 0; ni < 4; ni++)
      bfr[ni] = *(const ulonglong2*)(Bg + (size_t)(ni * 16 + n) * DIM + h * 64 +
                                     q * 16);
#pragma unroll
    for (int mi = 0; mi < 4; mi++)
#pragma unroll
      for (int ni = 0; ni < 4; ni++) {
        acc[mi * 4 + ni] = __builtin_amdgcn_mfma_f32_16x16x32_fp8_fp8(
            (long long)af[mi].x, (long long)bfr[ni].x, acc[mi * 4 + ni], 0, 0,
            0);
        acc[mi * 4 + ni] = __builtin_amdgcn_mfma_f32_16x16x32_fp8_fp8(
            (long long)af[mi].y, (long long)bfr[ni].y, acc[mi * 4 + ni], 0, 0,
            0);
      }
  }

  // epilogue: exp2, diagonal mask, row + column accumulation
  float eaccR[16];
  float eaccC[4] = {0.0f, 0.0f, 0.0f, 0.0f};
#pragma unroll
  for (int i = 0; i < 16; i++) eaccR[i] = 0.0f;
#pragma unroll
  for (int mi = 0; mi < 4; mi++) {
#pragma unroll
    for (int ni = 0; ni < 4; ni++) {
#pragma unroll
      for (int rg = 0; rg < 4; rg++) {
        float v = acc[mi * 4 + ni][rg];
        float e = __builtin_amdgcn_exp2f(v);
        int grow = rbBase + wrow + mi * 16 + q * 4 + rg;
        int gcol = cbBase + wcol + ni * 16 + n;
        e = (grow == gcol) ? 0.0f : e;
        eaccR[mi * 4 + rg] += e;
        eaccC[ni] += e;
      }
    }
  }
#pragma unroll
  for (int mi = 0; mi < 4; mi++) {
#pragma unroll
    for (int rg = 0; rg < 4; rg++) {
      float v = eaccR[mi * 4 + rg];
      v += __shfl_xor(v, 1);
      v += __shfl_xor(v, 2);
      v += __shfl_xor(v, 4);
      v += __shfl_xor(v, 8);
      if (n == 0)
        atomicAdd(&rowsum[rbBase + wrow + mi * 16 + q * 4 + rg], v);
    }
  }
  if (!diag) {
#pragma unroll
    for (int ni = 0; ni < 4; ni++) {
      float v = eaccC[ni];
      v += __shfl_xor(v, 16);
      v += __shfl_xor(v, 32);
      if (lane < 16) atomicAdd(&rowsum[cbBase + wcol + ni * 16 + n], v);
    }
  }

  // last-block finalize: loss = mean(log(rowsum) - pos)
  __threadfence();
  __shared__ unsigned int lastFlag;
  if (tid == 0) {
    unsigned int old = __hip_atomic_fetch_add(counter, 1u, __ATOMIC_ACQ_REL,
                                              __HIP_MEMORY_SCOPE_AGENT);
    lastFlag = (old == NTILES - 1) ? 1u : 0u;
  }
  __syncthreads();
  if (lastFlag) {
    float local = 0.0f;
    for (int r = tid; r < NROWS; r += 256) {
      float rs = __hip_atomic_load(&rowsum[r], __ATOMIC_RELAXED,
                                   __HIP_MEMORY_SCOPE_AGENT);
      local += __logf(rs) - pos[r];
    }
#pragma unroll
    for (int off = 1; off < 64; off <<= 1) local += __shfl_xor(local, off);
    __shared__ float wsum[4];
    if (lane == 0) wsum[w] = local;
    __syncthreads();
    if (tid == 0)
      out[0] = (wsum[0] + wsum[1] + wsum[2] + wsum[3]) * (1.0f / (float)NROWS);
  }
}

extern "C" void kernel_launch(void* const* d_in, const int* in_sizes, int n_in,
                              void* d_out, int out_size, void* d_ws,
                              size_t ws_size, hipStream_t stream) {
  const float* z_i = (const float*)d_in[0];
  const float* z_j = (const float*)d_in[1];
  float* out = (float*)d_out;

  unsigned char* A = (unsigned char*)d_ws;               // 8192*128 fp8 = 1 MB
  float* rowsum = (float*)((char*)d_ws + 1048576);       // 32 KB
  float* pos = (float*)((char*)d_ws + 1048576 + 32768);  // 32 KB
  unsigned int* counter = (unsigned int*)((char*)d_ws + 1048576 + 65536);

  prep_kernel<<<NHALF / 4, 256, 0, stream>>>(z_i, z_j, A, rowsum, pos, counter);
  simexp_kernel<<<NTILES, 256, 0, stream>>>(A, rowsum, pos, counter, out);
}